// Round 1
// baseline (408.782 us; speedup 1.0000x reference)
//
#include <hip/hip_runtime.h>
#include <math.h>

// LeftPool: out[b,c,h,w] = max(x[b,c,h,w:]) — reverse cummax along W (contiguous, 128).
// One 32-lane half-wave per row; each lane owns a float4 (4 consecutive floats).
// 16 B/lane coalesced loads/stores; suffix-max scan via clamped __shfl (max is
// idempotent so clamping the source lane to the segment end is correct).

__global__ __launch_bounds__(256) void leftpool_kernel(const float* __restrict__ x,
                                                       float* __restrict__ out) {
    const int row    = blockIdx.x * 8 + (threadIdx.x >> 5);   // 8 rows per 256-thread block
    const int laneId = threadIdx.x & 63;                      // lane within wave (wave=64)
    const int l      = laneId & 31;                           // lane within 32-lane row segment
    const int segBase = laneId & 32;                          // segment base lane in wave

    const float4* __restrict__ xin = (const float4*)(x + (size_t)row * 128);
    float4 v = xin[l];

    // local max of this lane's 4 elements
    float m = fmaxf(fmaxf(v.x, v.y), fmaxf(v.z, v.w));

    // inclusive suffix-max scan across the 32-lane segment
    #pragma unroll
    for (int off = 1; off < 32; off <<= 1) {
        int src = l + off;
        if (src > 31) src = 31;                 // clamp: max(v, dup) is harmless
        float other = __shfl(m, segBase + src);
        m = fmaxf(m, other);
    }

    // exclusive suffix-max (strictly right of this lane's 4 elements)
    int src1 = l + 1;
    if (src1 > 31) src1 = 31;
    float excl = __shfl(m, segBase + src1);
    if (l == 31) excl = -INFINITY;

    // reverse cummax within the lane's 4 elements
    float4 o;
    o.w = fmaxf(v.w, excl);
    o.z = fmaxf(v.z, o.w);
    o.y = fmaxf(v.y, o.z);
    o.x = fmaxf(v.x, o.y);

    float4* __restrict__ outv = (float4*)(out + (size_t)row * 128);
    outv[l] = o;
}

extern "C" void kernel_launch(void* const* d_in, const int* in_sizes, int n_in,
                              void* d_out, int out_size, void* d_ws, size_t ws_size,
                              hipStream_t stream) {
    const float* x = (const float*)d_in[0];
    float* out = (float*)d_out;

    const int W = 128;
    const int rows = in_sizes[0] / W;          // 16*256*128 = 524288
    const int rows_per_block = 8;              // 256 threads / 32 lanes-per-row
    dim3 grid(rows / rows_per_block);          // 65536 blocks
    leftpool_kernel<<<grid, 256, 0, stream>>>(x, out);
}